// Round 12
// baseline (108.393 us; speedup 1.0000x reference)
//
#include <hip/hip_runtime.h>
#include <math.h>

namespace {
constexpr int kH = 512;
constexpr int kN = 64;
constexpr int kL = 4096;
constexpr int kM = 2048;      // L/2
constexpr int kPairRec = 40;  // floats per n-PAIR record (160 B)
constexpr int kThreads = 256;
constexpr int kFftThreads = 512;
constexpr float kPi = 3.14159265358979323846f;
}

typedef float v2f __attribute__((ext_vector_type(2)));

__device__ __forceinline__ int lpad(int i) { return i + (i >> 4); }
__device__ __forceinline__ v2f fma2(v2f a, v2f b, v2f c) {
    return __builtin_elementwise_fma(a, b, c);
}
__device__ __forceinline__ float2 cmul(float2 a, float2 b) {
    return make_float2(a.x*b.x - a.y*b.y, a.x*b.y + a.y*b.x);
}

// ===================== Kernel 0: prep =====================
// One 64-thread block per head (blockIdx = h -> XCD h%8 under round-robin
// dispatch; its cst writes allocate in THAT XCD's L2 -- the spectrum kernel
// is swizzled to consume them on the same XCD).
// Pair-interleaved records: every coefficient pair (n even, n odd) is a
// consecutive 64-bit scalar pair -> legal SGPR-pair operand of v_pk_fma_f32.
//   s_r(l) = sum_n (a0 + a1*s)/D        s = 4t^2, t = tan(pi*l/L)
//   s_i(l) = t * sum_n (b0 + b1*s)/D    D = m1*m2, m = ar^2 + (2t -+ ai)^2
//   (D in PRODUCT form: polynomial-in-s cancels at resonances)
//   a0 = -2*C1*(vr*ar + vi*ai)          a1 = 2*(vi*ai - vr*ar)
//   b0 = -4*vr*(ar^2-ai^2) - 8*vi*ar*ai b1 = -4*vr       [C1 = ar^2+ai^2]
__global__ __launch_bounds__(64)
void s4_prep(const float* __restrict__ A_real, const float* __restrict__ A_imag,
             const float* __restrict__ Bv, const float* __restrict__ Cv,
             const float* __restrict__ Pv, const float* __restrict__ inv_dt,
             float* __restrict__ cst)
{
    const int h = blockIdx.x;
    const int n = threadIdx.x;
    const int idx = h * kN + n;
    const float dt = expf(inv_dt[h]);
    const float ar = -expf(A_real[idx]) * dt;   // Re(A*dt) (negative)
    const float ai =  A_imag[idx] * dt;         // Im(A*dt)
    const float br = Bv[idx*2+0], bi = Bv[idx*2+1];
    const float cr = Cv[idx*2+0], ci = Cv[idx*2+1];
    const float pr = Pv[idx*2+0], pi = Pv[idx*2+1];
    const float v00r = (br*cr - bi*ci)*dt, v00i = (br*ci + bi*cr)*dt;  // B*C
    const float v01r = (br*pr + bi*pi)*dt, v01i = (bi*pr - br*pi)*dt;  // B*conj(P)
    const float v10r = (pr*cr - pi*ci)*dt, v10i = (pr*ci + pi*cr)*dt;  // P*C
    const float v11r = (pr*pr + pi*pi)*dt;                              // |P|^2 (real)
    const float ar2 = ar*ar;
    const float C1  = ar2 + ai*ai;
    const float dd  = ar2 - ai*ai;

    float co[16];
    co[0]  = -2.f*C1*(v00r*ar + v00i*ai);   co[1]  = 2.f*(v00i*ai - v00r*ar);
    co[2]  = -4.f*v00r*dd - 8.f*v00i*ar*ai; co[3]  = -4.f*v00r;
    co[4]  = -2.f*C1*(v01r*ar + v01i*ai);   co[5]  = 2.f*(v01i*ai - v01r*ar);
    co[6]  = -4.f*v01r*dd - 8.f*v01i*ar*ai; co[7]  = -4.f*v01r;
    co[8]  = -2.f*C1*(v10r*ar + v10i*ai);   co[9]  = 2.f*(v10i*ai - v10r*ar);
    co[10] = -4.f*v10r*dd - 8.f*v10i*ar*ai; co[11] = -4.f*v10r;
    co[12] = -2.f*C1*(v11r*ar);             co[13] = -2.f*v11r*ar;
    co[14] = -4.f*v11r*dd;                  co[15] = -4.f*v11r;

    float* base = cst + ((size_t)h * (kN/2) + (n >> 1)) * kPairRec + (n & 1);
    base[0] = ai;
    base[2] = ar2;
    #pragma unroll
    for (int k = 0; k < 16; ++k) base[4 + 2*k] = co[k];
    // floats 36..39 unused padding
}

// ===================== Kernel 1: spectrum =====================
// grid = 2048 blocks, 256 threads, 2 bins/thread.
// XCD-ALIGNED: h = (b&7) + 8*((b>>3)&63) so all 4 blocks of head h run on
// XCD h%8 -- the XCD whose L2 holds prep's fresh cst[h] (R11: confirmed win).
// With the stream L2-warm (~200 cyc), 2 bins/thread gives 92 cyc of packed
// work per record; unroll-2 puts ~184 cyc between s_load issue and use --
// matching the L2 latency (this exact change REGRESSED in R5 when the
// stream was HBM-cold at ~900 cyc; the warm regime flips the tradeoff).
// Coefficient SGPR pairs are reused by both bins: no extra scalar traffic.
// NO min-waves launch bound (R7 spill disaster).
__global__ __launch_bounds__(kThreads)
void s4_spectrum(const float* __restrict__ cst, float2* __restrict__ Xg)
{
    const int b   = blockIdx.x;
    const int h   = (b & 7) + 8 * ((b >> 3) & 63);
    const int q   = b >> 9;              // 0..3
    const int tid = threadIdx.x;
    const int la  = q * 512 + tid;       // bins la and la+256

    float tvb[2], svb[2];
    v2f t2p[2];
    #pragma unroll
    for (int bb = 0; bb < 2; ++bb) {
        const int l = la + 256 * bb;
        float sn, cn;
        sincosf((float)l * (kPi / (float)kL), &sn, &cn);
        tvb[bb] = sn / cn;               // tan(pi*l/L), finite for l<=2047
        const float t2 = 2.f * tvb[bb];
        svb[bb] = t2 * t2;               // s = 4t^2
        t2p[bb] = (v2f){t2, t2};
    }

    // [bin][product {00,01,10,11}] packed even/odd-n partial sums
    v2f A0[2][4], A1[2][4], B0[2][4], B1[2][4];
    #pragma unroll
    for (int bb = 0; bb < 2; ++bb)
        #pragma unroll
        for (int p = 0; p < 4; ++p) {
            A0[bb][p] = (v2f){0.f, 0.f}; A1[bb][p] = (v2f){0.f, 0.f};
            B0[bb][p] = (v2f){0.f, 0.f}; B1[bb][p] = (v2f){0.f, 0.f};
        }

    const v2f* rec = (const v2f*)(cst + (size_t)h * (kN/2) * kPairRec);
    #pragma unroll 2
    for (int j = 0; j < kN/2; ++j) {
        const v2f* r = rec + j * (kPairRec/2);   // wave-uniform -> s_load
        const v2f aip  = r[0];
        const v2f ar2p = r[1];
        #pragma unroll
        for (int bb = 0; bb < 2; ++bb) {
            const v2f w1 = t2p[bb] - aip;
            const v2f w2 = t2p[bb] + aip;
            const v2f m1 = fma2(w1, w1, ar2p);
            const v2f m2 = fma2(w2, w2, ar2p);
            const v2f D  = m1 * m2;
            v2f qv;
            qv.x = __builtin_amdgcn_rcpf(D.x);
            qv.y = __builtin_amdgcn_rcpf(D.y);
            #pragma unroll
            for (int p = 0; p < 4; ++p) {
                A0[bb][p] = fma2(r[2 + 4*p + 0], qv, A0[bb][p]);
                A1[bb][p] = fma2(r[2 + 4*p + 1], qv, A1[bb][p]);
                B0[bb][p] = fma2(r[2 + 4*p + 2], qv, B0[bb][p]);
                B1[bb][p] = fma2(r[2 + 4*p + 3], qv, B1[bb][p]);
            }
        }
    }

    #pragma unroll
    for (int bb = 0; bb < 2; ++bb) {
        const int l = la + 256 * bb;
        const float t = tvb[bb];
        const v2f sp = (v2f){svb[bb], svb[bb]};
        const v2f r00 = fma2(sp, A1[bb][0], A0[bb][0]);
        const v2f i00 = fma2(sp, B1[bb][0], B0[bb][0]);
        const v2f r01 = fma2(sp, A1[bb][1], A0[bb][1]);
        const v2f i01 = fma2(sp, B1[bb][1], B0[bb][1]);
        const v2f r10 = fma2(sp, A1[bb][2], A0[bb][2]);
        const v2f i10 = fma2(sp, B1[bb][2], B0[bb][2]);
        const v2f r11 = fma2(sp, A1[bb][3], A0[bb][3]);
        const v2f i11 = fma2(sp, B1[bb][3], B0[bb][3]);
        const float s00r = r00.x + r00.y, s00i = t * (i00.x + i00.y);
        const float s01r = r01.x + r01.y, s01i = t * (i01.x + i01.y);
        const float s10r = r10.x + r10.y, s10i = t * (i10.x + i10.y);
        const float s11r = r11.x + r11.y, s11i = t * (i11.x + i11.y);
        const float nr = s01r*s10r - s01i*s10i;
        const float ni = s01r*s10i + s01i*s10r;
        const float dr = 1.f + s11r, di = s11i;
        const float qd = __builtin_amdgcn_rcpf(fmaf(dr, dr, di*di));
        const float wr = (nr*dr + ni*di) * qd;
        const float wi = (ni*dr - nr*di) * qd;
        const float gr = s00r - wr, gi = s00i - wi;
        // k_f = g * (1 + i*t)
        Xg[h*kM + l] = make_float2(fmaf(-gi, t, gr), fmaf(gr, t, gi));
    }
}

// ===================== Kernel 2: irfft =====================
// One 512-thread block per head (blockIdx = h -> XCD h%8: reads X[h] from
// the same XCD's L2 where spectrum's swizzled blocks wrote it).
// Packed-real 2048-pt inverse complex DFT in LDS; DIT stages fused pairwise
// into radix-4 passes (twA = twB^2, TW[pos+512] = i*TW[pos]); index padding
// i+(i>>4) breaks power-of-2 bank aliasing.
// Nyquist bin computed in-kernel: k_f[2048] = sum_n Re(B*C)*dt (real).
__global__ __launch_bounds__(kFftThreads)
void s4_ifft(const float* __restrict__ Bv,
             const float* __restrict__ Cv,
             const float* __restrict__ inv_dt,
             float* __restrict__ out)
{
    __shared__ float2 W2[kM + kM / 16];
    __shared__ float2 TW[kM / 2 + kM / 32];
    __shared__ float  XnyqR;

    const int h   = blockIdx.x;
    const int tid = threadIdx.x;
    const float2* Xg = (const float2*)(out + (size_t)h * kL);

    if (tid < kN) {   // wave 0: Nyquist bin
        const int idx = h * kN + tid;
        const float dt = expf(inv_dt[h]);
        const float br = Bv[idx*2+0], bi = Bv[idx*2+1];
        const float cr = Cv[idx*2+0], ci = Cv[idx*2+1];
        float vr = (br*cr - bi*ci) * dt;
        #pragma unroll
        for (int off = 32; off > 0; off >>= 1) vr += __shfl_down(vr, off, 64);
        if (tid == 0) XnyqR = vr;
    }
    for (int j = tid; j < kM / 2; j += kFftThreads) {
        float s, c;
        sincosf((2.0f * kPi / (float)kM) * (float)j, &s, &c);
        TW[lpad(j)] = make_float2(c, s);       // e^{+2pi i j / 2048}
    }
    __syncthreads();

    // build Z (bit-reversed) from global X:
    // E = (X[k]+conj(X[M-k]))/2 ; O = e^{+2pi i k/L}*(X[k]-conj(X[M-k]))/2
    // Z[k] = (Er-Oi, Ei+Or); Z[M-k] = (Er+Oi, Or-Ei)
    for (int k = tid; k <= kM / 2; k += kFftThreads) {
        const float2 Xa = Xg[k];
        const float2 Xb = (k == 0) ? make_float2(XnyqR, 0.0f) : Xg[kM - k];
        const float Er = 0.5f * (Xa.x + Xb.x);
        const float Ei = 0.5f * (Xa.y - Xb.y);
        const float Dr = 0.5f * (Xa.x - Xb.x);
        const float Di = 0.5f * (Xa.y + Xb.y);
        float s, c;
        sincosf((2.0f * kPi / (float)kL) * (float)k, &s, &c);
        const float Or = c * Dr - s * Di;
        const float Oi = c * Di + s * Dr;
        const int rk = (int)(__brev((unsigned)k) >> 21);          // 11-bit reversal
        W2[lpad(rk)] = make_float2(Er - Oi, Ei + Or);
        if (k != 0 && k != kM / 2) {
            const int rmk = (int)(__brev((unsigned)(kM - k)) >> 21);
            W2[lpad(rmk)] = make_float2(Er + Oi, Or - Ei);
        }
    }
    __syncthreads();

    // fused radix-4 passes: stages (hs, 2hs) for hs = 1,4,16,64,256
    #pragma unroll
    for (int lg = 0; lg <= 8; lg += 2) {
        const int hs = 1 << lg;
        const int twstride = 512 >> lg;      // 512/hs
        for (int j = tid; j < kM / 4; j += kFftThreads) {
            const int pos = j & (hs - 1);
            const int grp = j >> lg;
            const int i0  = grp * 4 * hs + pos;
            const float2 e0 = W2[lpad(i0)];
            const float2 e1 = W2[lpad(i0 + hs)];
            const float2 e2 = W2[lpad(i0 + 2*hs)];
            const float2 e3 = W2[lpad(i0 + 3*hs)];
            const float2 wB = TW[lpad(pos * twstride)];
            const float2 wA = cmul(wB, wB);
            const float2 t1 = cmul(wA, e1);
            const float2 t3 = cmul(wA, e3);
            const float2 a0 = make_float2(e0.x + t1.x, e0.y + t1.y);
            const float2 a1 = make_float2(e0.x - t1.x, e0.y - t1.y);
            const float2 a2 = make_float2(e2.x + t3.x, e2.y + t3.y);
            const float2 a3 = make_float2(e2.x - t3.x, e2.y - t3.y);
            const float2 u2 = cmul(wB, a2);
            const float2 u3 = cmul(wB, a3);
            W2[lpad(i0)]        = make_float2(a0.x + u2.x, a0.y + u2.y);
            W2[lpad(i0 + 2*hs)] = make_float2(a0.x - u2.x, a0.y - u2.y);
            W2[lpad(i0 + hs)]   = make_float2(a1.x - u3.y, a1.y + u3.x);  // a1 + i*u3
            W2[lpad(i0 + 3*hs)] = make_float2(a1.x + u3.y, a1.y - u3.x);  // a1 - i*u3
        }
        __syncthreads();
    }
    // final radix-2 stage, hs = 1024
    for (int j = tid; j < kM / 2; j += kFftThreads) {
        const float2 tw = TW[lpad(j)];
        const float2 a  = W2[lpad(j)];
        const float2 b  = W2[lpad(j + 1024)];
        const float2 tb = cmul(tw, b);
        W2[lpad(j)]        = make_float2(a.x + tb.x, a.y + tb.y);
        W2[lpad(j + 1024)] = make_float2(a.x - tb.x, a.y - tb.y);
    }
    __syncthreads();

    const float invM = 1.0f / (float)kM;
    float2* out2 = (float2*)(out + (size_t)h * kL);
    for (int n = tid; n < kM; n += kFftThreads) {
        const float2 zn = W2[lpad(n)];
        out2[n] = make_float2(zn.x * invM, zn.y * invM);
    }
}

extern "C" void kernel_launch(void* const* d_in, const int* in_sizes, int n_in,
                              void* d_out, int out_size, void* d_ws, size_t ws_size,
                              hipStream_t stream) {
    const float* A_real = (const float*)d_in[0];
    const float* A_imag = (const float*)d_in[1];
    const float* B      = (const float*)d_in[2];
    const float* C      = (const float*)d_in[3];
    const float* P      = (const float*)d_in[4];
    const float* inv_dt = (const float*)d_in[5];
    float* out = (float*)d_out;

    float* cst = (float*)d_ws;     // 512*32*40 floats = 2.62 MB

    s4_prep<<<dim3(kH), dim3(64), 0, stream>>>(A_real, A_imag, B, C, P, inv_dt,
                                               cst);
    s4_spectrum<<<dim3(kH * 4), dim3(kThreads), 0, stream>>>(cst, (float2*)out);
    s4_ifft<<<dim3(kH), dim3(kFftThreads), 0, stream>>>(B, C, inv_dt, out);
}

// Round 13
// 106.851 us; speedup vs baseline: 1.0144x; 1.0144x over previous
//
#include <hip/hip_runtime.h>
#include <math.h>

namespace {
constexpr int kH = 512;
constexpr int kN = 64;
constexpr int kL = 4096;
constexpr int kM = 2048;      // L/2
constexpr int kPairRec = 40;  // floats per n-PAIR record (160 B)
constexpr int kThreads = 256;
constexpr int kFftThreads = 512;
constexpr float kPi = 3.14159265358979323846f;
}

typedef float v2f __attribute__((ext_vector_type(2)));

__device__ __forceinline__ int lpad(int i) { return i + (i >> 4); }
__device__ __forceinline__ v2f fma2(v2f a, v2f b, v2f c) {
    return __builtin_elementwise_fma(a, b, c);
}
__device__ __forceinline__ float2 cmul(float2 a, float2 b) {
    return make_float2(a.x*b.x - a.y*b.y, a.x*b.y + a.y*b.x);
}

// ===================== Kernel 0: prep =====================
// One 64-thread block per head (blockIdx = h -> XCD h%8 under round-robin
// dispatch; its cst writes allocate in THAT XCD's L2 -- the spectrum kernel
// is swizzled to consume them on the same XCD). Also computes the (real)
// Nyquist value xnyq[h] = sum_n Re(B*C)*dt via in-wave reduction.
// Pair-interleaved records: every coefficient pair (n even, n odd) is a
// consecutive 64-bit scalar pair -> legal SGPR-pair operand of v_pk_fma_f32.
//   s_r(l) = sum_n (a0 + a1*s)/D        s = 4t^2, t = tan(pi*l/L)
//   s_i(l) = t * sum_n (b0 + b1*s)/D    D = m1*m2, m = ar^2 + (2t -+ ai)^2
//   (D in PRODUCT form: polynomial-in-s cancels at resonances)
//   a0 = -2*C1*(vr*ar + vi*ai)          a1 = 2*(vi*ai - vr*ar)
//   b0 = -4*vr*(ar^2-ai^2) - 8*vi*ar*ai b1 = -4*vr       [C1 = ar^2+ai^2]
__global__ __launch_bounds__(64)
void s4_prep(const float* __restrict__ A_real, const float* __restrict__ A_imag,
             const float* __restrict__ Bv, const float* __restrict__ Cv,
             const float* __restrict__ Pv, const float* __restrict__ inv_dt,
             float* __restrict__ cst, float* __restrict__ xnyq)
{
    const int h = blockIdx.x;
    const int n = threadIdx.x;
    const int idx = h * kN + n;
    const float dt = expf(inv_dt[h]);
    const float ar = -expf(A_real[idx]) * dt;   // Re(A*dt) (negative)
    const float ai =  A_imag[idx] * dt;         // Im(A*dt)
    const float br = Bv[idx*2+0], bi = Bv[idx*2+1];
    const float cr = Cv[idx*2+0], ci = Cv[idx*2+1];
    const float pr = Pv[idx*2+0], pi = Pv[idx*2+1];
    const float v00r = (br*cr - bi*ci)*dt, v00i = (br*ci + bi*cr)*dt;  // B*C
    const float v01r = (br*pr + bi*pi)*dt, v01i = (bi*pr - br*pi)*dt;  // B*conj(P)
    const float v10r = (pr*cr - pi*ci)*dt, v10i = (pr*ci + pi*cr)*dt;  // P*C
    const float v11r = (pr*pr + pi*pi)*dt;                              // |P|^2 (real)
    const float ar2 = ar*ar;
    const float C1  = ar2 + ai*ai;
    const float dd  = ar2 - ai*ai;

    float co[16];
    co[0]  = -2.f*C1*(v00r*ar + v00i*ai);   co[1]  = 2.f*(v00i*ai - v00r*ar);
    co[2]  = -4.f*v00r*dd - 8.f*v00i*ar*ai; co[3]  = -4.f*v00r;
    co[4]  = -2.f*C1*(v01r*ar + v01i*ai);   co[5]  = 2.f*(v01i*ai - v01r*ar);
    co[6]  = -4.f*v01r*dd - 8.f*v01i*ar*ai; co[7]  = -4.f*v01r;
    co[8]  = -2.f*C1*(v10r*ar + v10i*ai);   co[9]  = 2.f*(v10i*ai - v10r*ar);
    co[10] = -4.f*v10r*dd - 8.f*v10i*ar*ai; co[11] = -4.f*v10r;
    co[12] = -2.f*C1*(v11r*ar);             co[13] = -2.f*v11r*ar;
    co[14] = -4.f*v11r*dd;                  co[15] = -4.f*v11r;

    float* base = cst + ((size_t)h * (kN/2) + (n >> 1)) * kPairRec + (n & 1);
    base[0] = ai;
    base[2] = ar2;
    #pragma unroll
    for (int k = 0; k < 16; ++k) base[4 + 2*k] = co[k];
    // floats 36..39 unused padding

    // Nyquist (u=0): k_f[2048] = sum_n Re(B*C)*dt (real); block = one wave
    float s = v00r;
    #pragma unroll
    for (int off = 32; off > 0; off >>= 1) s += __shfl_down(s, off, 64);
    if (n == 0) xnyq[h] = s;
}

// ===================== Kernel 1: spectrum =====================
// grid = 2048 blocks, 256 threads, 2 bins/thread.
// XCD-ALIGNED: h = (b&7) + 8*((b>>3)&63) so all 4 blocks of head h run on
// XCD h%8 -- the XCD whose L2 holds prep's fresh cst[h] (R11: confirmed win).
// Packed across adjacent n (v_pk_fma_f32 with SGPR-pair coefficients from
// wave-uniform s_load); ONE rcp per n-pair via qq = rcp(D.x*D.y),
// qv = {D.y*qq, D.x*qq} -- trades a quarter-rate transcendental for two
// full-rate muls. Range-safe: D in [6e-14, 5e13] -> product in fp32 range.
// NO min-waves launch bound (R7 spill disaster).
__global__ __launch_bounds__(kThreads)
void s4_spectrum(const float* __restrict__ cst, float2* __restrict__ Xg)
{
    const int b   = blockIdx.x;
    const int h   = (b & 7) + 8 * ((b >> 3) & 63);
    const int q   = b >> 9;              // 0..3
    const int tid = threadIdx.x;
    const int la  = q * 512 + tid;       // bins la and la+256

    float tvb[2], svb[2];
    v2f t2p[2];
    #pragma unroll
    for (int bb = 0; bb < 2; ++bb) {
        const int l = la + 256 * bb;
        float sn, cn;
        sincosf((float)l * (kPi / (float)kL), &sn, &cn);
        tvb[bb] = sn / cn;               // tan(pi*l/L), finite for l<=2047
        const float t2 = 2.f * tvb[bb];
        svb[bb] = t2 * t2;               // s = 4t^2
        t2p[bb] = (v2f){t2, t2};
    }

    // [bin][product {00,01,10,11}] packed even/odd-n partial sums
    v2f A0[2][4], A1[2][4], B0[2][4], B1[2][4];
    #pragma unroll
    for (int bb = 0; bb < 2; ++bb)
        #pragma unroll
        for (int p = 0; p < 4; ++p) {
            A0[bb][p] = (v2f){0.f, 0.f}; A1[bb][p] = (v2f){0.f, 0.f};
            B0[bb][p] = (v2f){0.f, 0.f}; B1[bb][p] = (v2f){0.f, 0.f};
        }

    const v2f* rec = (const v2f*)(cst + (size_t)h * (kN/2) * kPairRec);
    #pragma unroll 2
    for (int j = 0; j < kN/2; ++j) {
        const v2f* r = rec + j * (kPairRec/2);   // wave-uniform -> s_load
        const v2f aip  = r[0];
        const v2f ar2p = r[1];
        #pragma unroll
        for (int bb = 0; bb < 2; ++bb) {
            const v2f w1 = t2p[bb] - aip;
            const v2f w2 = t2p[bb] + aip;
            const v2f m1 = fma2(w1, w1, ar2p);
            const v2f m2 = fma2(w2, w2, ar2p);
            const v2f D  = m1 * m2;
            const float qq = __builtin_amdgcn_rcpf(D.x * D.y);
            v2f qv;
            qv.x = D.y * qq;
            qv.y = D.x * qq;
            #pragma unroll
            for (int p = 0; p < 4; ++p) {
                A0[bb][p] = fma2(r[2 + 4*p + 0], qv, A0[bb][p]);
                A1[bb][p] = fma2(r[2 + 4*p + 1], qv, A1[bb][p]);
                B0[bb][p] = fma2(r[2 + 4*p + 2], qv, B0[bb][p]);
                B1[bb][p] = fma2(r[2 + 4*p + 3], qv, B1[bb][p]);
            }
        }
    }

    #pragma unroll
    for (int bb = 0; bb < 2; ++bb) {
        const int l = la + 256 * bb;
        const float t = tvb[bb];
        const v2f sp = (v2f){svb[bb], svb[bb]};
        const v2f r00 = fma2(sp, A1[bb][0], A0[bb][0]);
        const v2f i00 = fma2(sp, B1[bb][0], B0[bb][0]);
        const v2f r01 = fma2(sp, A1[bb][1], A0[bb][1]);
        const v2f i01 = fma2(sp, B1[bb][1], B0[bb][1]);
        const v2f r10 = fma2(sp, A1[bb][2], A0[bb][2]);
        const v2f i10 = fma2(sp, B1[bb][2], B0[bb][2]);
        const v2f r11 = fma2(sp, A1[bb][3], A0[bb][3]);
        const v2f i11 = fma2(sp, B1[bb][3], B0[bb][3]);
        const float s00r = r00.x + r00.y, s00i = t * (i00.x + i00.y);
        const float s01r = r01.x + r01.y, s01i = t * (i01.x + i01.y);
        const float s10r = r10.x + r10.y, s10i = t * (i10.x + i10.y);
        const float s11r = r11.x + r11.y, s11i = t * (i11.x + i11.y);
        const float nr = s01r*s10r - s01i*s10i;
        const float ni = s01r*s10i + s01i*s10r;
        const float dr = 1.f + s11r, di = s11i;
        const float qd = __builtin_amdgcn_rcpf(fmaf(dr, dr, di*di));
        const float wr = (nr*dr + ni*di) * qd;
        const float wi = (ni*dr - nr*di) * qd;
        const float gr = s00r - wr, gi = s00i - wi;
        // k_f = g * (1 + i*t)
        Xg[h*kM + l] = make_float2(fmaf(-gi, t, gr), fmaf(gr, t, gi));
    }
}

// ===================== Kernel 2: irfft =====================
// One 512-thread block per head (blockIdx = h -> XCD h%8: reads X[h] from
// the same XCD's L2 where spectrum's swizzled blocks wrote it).
// Packed-real 2048-pt inverse complex DFT in LDS; DIT stages fused pairwise
// into radix-4 passes (twA = twB^2, TW[pos+512] = i*TW[pos]); the FIRST pass
// (hs=1, all twiddles = 1) is special-cased with no cmuls/TW reads.
// Index padding i+(i>>4) breaks power-of-2 bank aliasing.
__global__ __launch_bounds__(kFftThreads)
void s4_ifft(const float* __restrict__ xnyq, float* __restrict__ out)
{
    __shared__ float2 W2[kM + kM / 16];
    __shared__ float2 TW[kM / 2 + kM / 32];

    const int h   = blockIdx.x;
    const int tid = threadIdx.x;
    const float2* Xg = (const float2*)(out + (size_t)h * kL);
    const float nyqR = xnyq[h];

    for (int j = tid; j < kM / 2; j += kFftThreads) {
        float s, c;
        sincosf((2.0f * kPi / (float)kM) * (float)j, &s, &c);
        TW[lpad(j)] = make_float2(c, s);       // e^{+2pi i j / 2048}
    }

    // build Z (bit-reversed) from global X:
    // E = (X[k]+conj(X[M-k]))/2 ; O = e^{+2pi i k/L}*(X[k]-conj(X[M-k]))/2
    // Z[k] = (Er-Oi, Ei+Or); Z[M-k] = (Er+Oi, Or-Ei)
    for (int k = tid; k <= kM / 2; k += kFftThreads) {
        const float2 Xa = Xg[k];
        const float2 Xb = (k == 0) ? make_float2(nyqR, 0.0f) : Xg[kM - k];
        const float Er = 0.5f * (Xa.x + Xb.x);
        const float Ei = 0.5f * (Xa.y - Xb.y);
        const float Dr = 0.5f * (Xa.x - Xb.x);
        const float Di = 0.5f * (Xa.y + Xb.y);
        float s, c;
        sincosf((2.0f * kPi / (float)kL) * (float)k, &s, &c);
        const float Or = c * Dr - s * Di;
        const float Oi = c * Di + s * Dr;
        const int rk = (int)(__brev((unsigned)k) >> 21);          // 11-bit reversal
        W2[lpad(rk)] = make_float2(Er - Oi, Ei + Or);
        if (k != 0 && k != kM / 2) {
            const int rmk = (int)(__brev((unsigned)(kM - k)) >> 21);
            W2[lpad(rmk)] = make_float2(Er + Oi, Or - Ei);
        }
    }
    __syncthreads();

    // first radix-4 pass (hs=1): wB = wA = 1 -- no twiddle loads, no cmuls
    for (int j = tid; j < kM / 4; j += kFftThreads) {
        const int i0 = j * 4;
        const float2 e0 = W2[lpad(i0)];
        const float2 e1 = W2[lpad(i0 + 1)];
        const float2 e2 = W2[lpad(i0 + 2)];
        const float2 e3 = W2[lpad(i0 + 3)];
        const float2 a0 = make_float2(e0.x + e1.x, e0.y + e1.y);
        const float2 a1 = make_float2(e0.x - e1.x, e0.y - e1.y);
        const float2 a2 = make_float2(e2.x + e3.x, e2.y + e3.y);
        const float2 a3 = make_float2(e2.x - e3.x, e2.y - e3.y);
        W2[lpad(i0)]     = make_float2(a0.x + a2.x, a0.y + a2.y);
        W2[lpad(i0 + 2)] = make_float2(a0.x - a2.x, a0.y - a2.y);
        W2[lpad(i0 + 1)] = make_float2(a1.x - a3.y, a1.y + a3.x);  // a1 + i*a3
        W2[lpad(i0 + 3)] = make_float2(a1.x + a3.y, a1.y - a3.x);  // a1 - i*a3
    }
    __syncthreads();

    // remaining fused radix-4 passes: stages (hs, 2hs) for hs = 4,16,64,256
    #pragma unroll
    for (int lg = 2; lg <= 8; lg += 2) {
        const int hs = 1 << lg;
        const int twstride = 512 >> lg;      // 512/hs
        for (int j = tid; j < kM / 4; j += kFftThreads) {
            const int pos = j & (hs - 1);
            const int grp = j >> lg;
            const int i0  = grp * 4 * hs + pos;
            const float2 e0 = W2[lpad(i0)];
            const float2 e1 = W2[lpad(i0 + hs)];
            const float2 e2 = W2[lpad(i0 + 2*hs)];
            const float2 e3 = W2[lpad(i0 + 3*hs)];
            const float2 wB = TW[lpad(pos * twstride)];
            const float2 wA = cmul(wB, wB);
            const float2 t1 = cmul(wA, e1);
            const float2 t3 = cmul(wA, e3);
            const float2 a0 = make_float2(e0.x + t1.x, e0.y + t1.y);
            const float2 a1 = make_float2(e0.x - t1.x, e0.y - t1.y);
            const float2 a2 = make_float2(e2.x + t3.x, e2.y + t3.y);
            const float2 a3 = make_float2(e2.x - t3.x, e2.y - t3.y);
            const float2 u2 = cmul(wB, a2);
            const float2 u3 = cmul(wB, a3);
            W2[lpad(i0)]        = make_float2(a0.x + u2.x, a0.y + u2.y);
            W2[lpad(i0 + 2*hs)] = make_float2(a0.x - u2.x, a0.y - u2.y);
            W2[lpad(i0 + hs)]   = make_float2(a1.x - u3.y, a1.y + u3.x);  // a1 + i*u3
            W2[lpad(i0 + 3*hs)] = make_float2(a1.x + u3.y, a1.y - u3.x);  // a1 - i*u3
        }
        __syncthreads();
    }
    // final radix-2 stage, hs = 1024
    for (int j = tid; j < kM / 2; j += kFftThreads) {
        const float2 tw = TW[lpad(j)];
        const float2 a  = W2[lpad(j)];
        const float2 b  = W2[lpad(j + 1024)];
        const float2 tb = cmul(tw, b);
        W2[lpad(j)]        = make_float2(a.x + tb.x, a.y + tb.y);
        W2[lpad(j + 1024)] = make_float2(a.x - tb.x, a.y - tb.y);
    }
    __syncthreads();

    const float invM = 1.0f / (float)kM;
    float2* out2 = (float2*)(out + (size_t)h * kL);
    for (int n = tid; n < kM; n += kFftThreads) {
        const float2 zn = W2[lpad(n)];
        out2[n] = make_float2(zn.x * invM, zn.y * invM);
    }
}

extern "C" void kernel_launch(void* const* d_in, const int* in_sizes, int n_in,
                              void* d_out, int out_size, void* d_ws, size_t ws_size,
                              hipStream_t stream) {
    const float* A_real = (const float*)d_in[0];
    const float* A_imag = (const float*)d_in[1];
    const float* B      = (const float*)d_in[2];
    const float* C      = (const float*)d_in[3];
    const float* P      = (const float*)d_in[4];
    const float* inv_dt = (const float*)d_in[5];
    float* out = (float*)d_out;

    float* cst  = (float*)d_ws;                        // 512*32*40 floats = 2.62 MB
    float* xnyq = cst + (size_t)kH * (kN/2) * kPairRec;

    s4_prep<<<dim3(kH), dim3(64), 0, stream>>>(A_real, A_imag, B, C, P, inv_dt,
                                               cst, xnyq);
    s4_spectrum<<<dim3(kH * 4), dim3(kThreads), 0, stream>>>(cst, (float2*)out);
    s4_ifft<<<dim3(kH), dim3(kFftThreads), 0, stream>>>(xnyq, out);
}